// Round 1
// baseline (1113.746 us; speedup 1.0000x reference)
//
#include <hip/hip_runtime.h>
#include <math.h>

#define NEG -1e30f
#define GS 260  // padded gathered-emission row stride in floats: [blank, S targets, pad]

// ---------------- wave64 reductions ----------------
__device__ inline float wave_max(float v) {
#pragma unroll
  for (int off = 32; off > 0; off >>= 1) v = fmaxf(v, __shfl_xor(v, off, 64));
  return v;
}
__device__ inline float wave_sum(float v) {
#pragma unroll
  for (int off = 32; off > 0; off >>= 1) v += __shfl_xor(v, off, 64);
  return v;
}

// ---------------- K1: log-softmax + gather ----------------
// grid: (Tc/4, B), block: 256 (4 waves, one row per wave)
__global__ __launch_bounds__(256) void k1_gather(
    const float* __restrict__ lp, const int* __restrict__ targets,
    float* __restrict__ g, int t0, int T, int Tc, int S, int C) {
  __shared__ __align__(16) float rowbuf[4][1024];
  const int w = threadIdx.x >> 6;
  const int lane = threadIdx.x & 63;
  const int tloc = blockIdx.x * 4 + w;
  const int b = blockIdx.y;
  const int t = t0 + tloc;

  const float* row = lp + ((size_t)b * T + t) * (size_t)C;

  float x[16];
#pragma unroll
  for (int j = 0; j < 4; ++j) {
    float4 v = *(const float4*)(row + j * 256 + lane * 4);
    x[4 * j + 0] = v.x; x[4 * j + 1] = v.y;
    x[4 * j + 2] = v.z; x[4 * j + 3] = v.w;
  }
  float m = x[0];
#pragma unroll
  for (int k = 1; k < 16; ++k) m = fmaxf(m, x[k]);
  m = wave_max(m);
  float s = 0.f;
#pragma unroll
  for (int k = 0; k < 16; ++k) s += __expf(x[k] - m);
  s = wave_sum(s);
  const float lse = m + __logf(s);

#pragma unroll
  for (int j = 0; j < 4; ++j) {
    *(float4*)(&rowbuf[w][j * 256 + lane * 4]) =
        make_float4(x[4 * j + 0], x[4 * j + 1], x[4 * j + 2], x[4 * j + 3]);
  }
  __syncthreads();

  float* gr = g + ((size_t)b * Tc + tloc) * GS;
  const int* tg = targets + (size_t)b * S;
  for (int i = lane; i <= S; i += 64) {  // 257 gathered values
    const int cls = (i == 0) ? 0 : tg[i - 1];
    gr[i] = rowbuf[w][cls] - lse;
  }
}

// ---------------- K2: sequential alpha recursion ----------------
// grid: (B), block: 512.  State s handled by thread s; thread 0 also does s=512.
__global__ __launch_bounds__(512) void k2_alpha(
    const float* __restrict__ g, const int* __restrict__ targets,
    const int* __restrict__ in_len, const int* __restrict__ tgt_len,
    float* __restrict__ alpha_g, float* __restrict__ tot,
    int t0, int Tc, int S, int is_first, int is_last) {
  const int b = blockIdx.x;
  const int tid = threadIdx.x;
  __shared__ float al[2][520];

  const int len = in_len[b];
  const int tl = tgt_len[b];
  const float* gb = g + (size_t)b * Tc * GS;
  const int* tg = targets + (size_t)b * S;

  const int s = tid;
  const int odd = s & 1;
  const int ci = odd ? ((s >> 1) + 1) : 0;  // emission index into gathered row
  const bool cs = odd && (s >= 3) && (tg[s >> 1] != tg[(s >> 1) - 1]);

  if (is_first) {
    const float e = gb[ci];  // t = 0 emissions (tloc 0)
    al[0][s] = ((s < 2) ? 0.0f : NEG) + e;
    if (tid == 0) al[0][512] = NEG + gb[0];
  } else {
    al[0][s] = alpha_g[(size_t)b * 513 + s];
    if (tid == 0) al[0][512] = alpha_g[(size_t)b * 513 + 512];
  }
  __syncthreads();

  int cur = 0;
  const int tstart = is_first ? 1 : t0;
  const int t_hi = min(t0 + Tc, len);  // freeze: no updates for t >= len

  float ep = 0.f, ep2 = 0.f;
  if (tstart < t_hi) {
    ep = gb[(size_t)(tstart - t0) * GS + ci];
    if (tid == 0) ep2 = gb[(size_t)(tstart - t0) * GS];
  }

  for (int tt = tstart; tt < t_hi; ++tt) {
    const float e0 = ep;
    const float e02 = ep2;
    if (tt + 1 < t_hi) {  // prefetch next emission before barrier
      ep = gb[(size_t)(tt + 1 - t0) * GS + ci];
      if (tid == 0) ep2 = gb[(size_t)(tt + 1 - t0) * GS];
    }
    const float a0 = al[cur][s];
    const float a1 = (s >= 1) ? al[cur][s - 1] : NEG;
    const float a2 = cs ? al[cur][s - 2] : NEG;
    const float m = fmaxf(fmaxf(a0, a1), a2);
    const float r =
        m + __logf(__expf(a0 - m) + __expf(a1 - m) + __expf(a2 - m)) + e0;
    al[cur ^ 1][s] = r;
    if (tid == 0) {  // state 512 (blank)
      const float b0 = al[cur][512], b1 = al[cur][511];
      const float mm = fmaxf(b0, b1);
      al[cur ^ 1][512] = mm + __logf(__expf(b0 - mm) + __expf(b1 - mm)) + e02;
    }
    __syncthreads();
    cur ^= 1;
  }

  if (is_last) {
    if (tid == 0) {
      const int i1 = 2 * tl;
      const int i2 = (2 * tl - 1 > 0) ? (2 * tl - 1) : 0;
      const float a1v = al[cur][i1];
      const float a2v = (tl > 0) ? al[cur][i2] : NEG;
      const float mm = fmaxf(a1v, a2v);
      tot[b] = mm + __logf(__expf(a1v - mm) + __expf(a2v - mm));
    }
  } else {
    alpha_g[(size_t)b * 513 + s] = al[cur][s];
    if (tid == 0) alpha_g[(size_t)b * 513 + 512] = al[cur][512];
  }
}

// ---------------- K3: -mean over batch ----------------
__global__ void k3_mean(const float* __restrict__ tot, float* __restrict__ out,
                        int B) {
  float v = (threadIdx.x < B) ? tot[threadIdx.x] : 0.0f;
  v = wave_sum(v);
  if (threadIdx.x == 0) out[0] = -v / (float)B;
}

// ---------------- host ----------------
extern "C" void kernel_launch(void* const* d_in, const int* in_sizes, int n_in,
                              void* d_out, int out_size, void* d_ws,
                              size_t ws_size, hipStream_t stream) {
  const float* lp = (const float*)d_in[0];
  const int* targets = (const int*)d_in[1];
  const int* in_len = (const int*)d_in[2];
  const int* tgt_len = (const int*)d_in[3];
  float* out = (float*)d_out;

  const int B = in_sizes[2];              // 64
  const int S = in_sizes[1] / B;          // 256
  const int C = 1024;                     // fixed by reference
  const int T = (int)((size_t)in_sizes[0] / ((size_t)B * C));  // 2048

  // workspace layout: tot[B] | alpha_g[B*513] | g[B*Tc*GS]
  float* tot = (float*)d_ws;
  float* alpha_g = tot + 64;
  float* g = alpha_g + (size_t)B * 513;
  const size_t head = (64 + (size_t)B * 513) * sizeof(float);

  int Tc = T;
  while (Tc > 32 && head + (size_t)B * Tc * GS * sizeof(float) > ws_size)
    Tc >>= 1;

  const int nch = (T + Tc - 1) / Tc;
  for (int c = 0; c < nch; ++c) {
    const int t0 = c * Tc;
    dim3 g1(Tc / 4, B);
    k1_gather<<<g1, 256, 0, stream>>>(lp, targets, g, t0, T, Tc, S, C);
    k2_alpha<<<B, 512, 0, stream>>>(g, targets, in_len, tgt_len, alpha_g, tot,
                                    t0, Tc, S, (c == 0) ? 1 : 0,
                                    (c == nch - 1) ? 1 : 0);
  }
  k3_mean<<<1, 64, 0, stream>>>(tot, out, B);
}

// Round 2
// 522.475 us; speedup vs baseline: 2.1317x; 2.1317x over previous
//
#include <hip/hip_runtime.h>
#include <math.h>

#define GS 260  // gathered-emission row stride (floats): [p_tg0..p_tg255, pad3, p_blank@256]

// ---------------- wave64 reductions ----------------
__device__ inline float wave_max(float v) {
#pragma unroll
  for (int off = 32; off > 0; off >>= 1) v = fmaxf(v, __shfl_xor(v, off, 64));
  return v;
}
__device__ inline float wave_sum(float v) {
#pragma unroll
  for (int off = 32; off > 0; off >>= 1) v += __shfl_xor(v, off, 64);
  return v;
}

// ---------------- K1: log-softmax + gather -> linear probs ----------------
// grid: (Tc/4, B), block 256 (4 waves, one (b,t) row per wave)
__global__ __launch_bounds__(256) void k1_gather(
    const float* __restrict__ lp, const int* __restrict__ targets,
    float* __restrict__ g, int t0, int T, int Tc, int S, int C) {
  __shared__ __align__(16) float rowbuf[4][1024];
  const int w = threadIdx.x >> 6;
  const int lane = threadIdx.x & 63;
  const int tloc = blockIdx.x * 4 + w;
  const int b = blockIdx.y;
  const int t = t0 + tloc;

  const float* row = lp + ((size_t)b * T + t) * (size_t)C;

  float x[16];
#pragma unroll
  for (int j = 0; j < 4; ++j) {
    float4 v = *(const float4*)(row + j * 256 + lane * 4);
    x[4 * j + 0] = v.x; x[4 * j + 1] = v.y;
    x[4 * j + 2] = v.z; x[4 * j + 3] = v.w;
  }
  float m = x[0];
#pragma unroll
  for (int k = 1; k < 16; ++k) m = fmaxf(m, x[k]);
  m = wave_max(m);
  float s = 0.f;
#pragma unroll
  for (int k = 0; k < 16; ++k) s += __expf(x[k] - m);
  s = wave_sum(s);
  const float lse = m + __logf(s);

#pragma unroll
  for (int j = 0; j < 4; ++j) {
    *(float4*)(&rowbuf[w][j * 256 + lane * 4]) =
        make_float4(x[4 * j + 0], x[4 * j + 1], x[4 * j + 2], x[4 * j + 3]);
  }
  __syncthreads();

  float* gr = g + ((size_t)b * Tc + tloc) * GS;
  const int* tg = targets + (size_t)b * S;
  for (int i = lane; i <= S; i += 64) {   // i==S is the blank slot
    const int cls = (i == S) ? 0 : tg[i];
    gr[i] = __expf(rowbuf[w][cls] - lse);
  }
}

// ---------------- K2: linear-domain alpha recursion, 1 wave per batch ----
// lane l owns states [8l, 8l+8); lane 63 also owns state 512.
__global__ __launch_bounds__(64) void k2_alpha(
    const float* __restrict__ g, const int* __restrict__ targets,
    const int* __restrict__ in_len, const int* __restrict__ tgt_len,
    float* __restrict__ alpha_g, int* __restrict__ exp_g,
    float* __restrict__ tot, int t0, int Tc, int S, int is_first, int is_last) {
  const int b = blockIdx.x;
  const int lane = threadIdx.x;
  const float* gb = g + (size_t)b * Tc * GS;
  const int len = in_len[b];
  const int tl = tgt_len[b];
  const int* tg = targets + (size_t)b * S;

  // skip-transition multipliers for odd local states j=1,3,5,7
  const int4 mytg = *(const int4*)(tg + 4 * lane);
  const int tgm1 = (lane > 0) ? tg[4 * lane - 1] : -1;
  const float sk1 = (lane > 0 && mytg.x != tgm1) ? 1.f : 0.f;
  const float sk3 = (mytg.y != mytg.x) ? 1.f : 0.f;
  const float sk5 = (mytg.z != mytg.y) ? 1.f : 0.f;
  const float sk7 = (mytg.w != mytg.z) ? 1.f : 0.f;

  float a0, a1, a2, a3, a4, a5, a6, a7, a8;
  int E;
  int tstart;
  if (is_first) {
    a0 = a1 = a2 = a3 = a4 = a5 = a6 = a7 = a8 = 0.f;
    if (lane == 0) { a0 = gb[S]; a1 = gb[0]; }  // t=0: blank, first label
    E = 0;
    tstart = 1;
  } else {
    const float* ap = alpha_g + (size_t)b * 520 + 8 * lane;
    a0 = ap[0]; a1 = ap[1]; a2 = ap[2]; a3 = ap[3];
    a4 = ap[4]; a5 = ap[5]; a6 = ap[6]; a7 = ap[7];
    a8 = (lane == 63) ? alpha_g[(size_t)b * 520 + 512] : 0.f;
    E = exp_g[b];
    tstart = t0;
  }

  const int t_hi = min(t0 + Tc, len);
  int N = t_hi - tstart; if (N < 0) N = 0;
  const int G = (N + 3) >> 2;
  const int tsrel = tstart - t0;
  const int TcM1 = Tc - 1;

#define LOADG(P, Q, gbase)                                     \
  {                                                            \
    _Pragma("unroll") for (int k = 0; k < 4; ++k) {            \
      int tr = tsrel + (gbase) * 4 + k;                        \
      tr = (tr < TcM1) ? tr : TcM1;                            \
      const float* rp = gb + (size_t)tr * GS;                  \
      P[k] = *(const float4*)(rp + 4 * lane);                  \
      Q[k] = rp[256];                                          \
    }                                                          \
  }

#define STEP(pt, pbv)                                          \
  {                                                            \
    float hm1 = __shfl_up(a7, 1, 64);                          \
    hm1 = (lane == 0) ? 0.f : hm1;                             \
    const float n0 = (a0 + hm1) * (pbv);                       \
    const float n1 = __fmaf_rn(sk1, hm1, a1 + a0) * (pt).x;    \
    const float n2 = (a2 + a1) * (pbv);                        \
    const float n3 = __fmaf_rn(sk3, a1, a3 + a2) * (pt).y;     \
    const float n4 = (a4 + a3) * (pbv);                        \
    const float n5 = __fmaf_rn(sk5, a3, a5 + a4) * (pt).z;     \
    const float n6 = (a6 + a5) * (pbv);                        \
    const float n7 = __fmaf_rn(sk7, a5, a7 + a6) * (pt).w;     \
    const float n8 = (a8 + a7) * (pbv);                        \
    a0 = n0; a1 = n1; a2 = n2; a3 = n3; a4 = n4;               \
    a5 = n5; a6 = n6; a7 = n7; a8 = n8;                        \
  }

#define RESCALE()                                                         \
  {                                                                       \
    float m_ = fmaxf(fmaxf(fmaxf(fmaxf(a0, a1), fmaxf(a2, a3)),          \
                           fmaxf(fmaxf(a4, a5), fmaxf(a6, a7))), a8);    \
    m_ = wave_max(m_);                                                    \
    const int e_ =                                                        \
        (m_ > 0.f) ? (int)((__float_as_uint(m_) >> 23) & 255u) - 127 : 0; \
    a0 = ldexpf(a0, -e_); a1 = ldexpf(a1, -e_); a2 = ldexpf(a2, -e_);     \
    a3 = ldexpf(a3, -e_); a4 = ldexpf(a4, -e_); a5 = ldexpf(a5, -e_);     \
    a6 = ldexpf(a6, -e_); a7 = ldexpf(a7, -e_); a8 = ldexpf(a8, -e_);     \
    E += e_;                                                              \
  }

#define STEPS(P, Q, gbase)                                     \
  {                                                            \
    const int rem = N - (gbase) * 4;                           \
    if (rem > 0) {                                             \
      STEP(P[0], Q[0]);                                        \
      if (rem > 1) STEP(P[1], Q[1]);                           \
      if (rem > 2) STEP(P[2], Q[2]);                           \
      if (rem > 3) STEP(P[3], Q[3]);                           \
      RESCALE();                                               \
    }                                                          \
  }

  float4 PA[4], PB[4], PC[4];
  float QA[4], QB[4], QC[4];
  LOADG(PA, QA, 0);
  LOADG(PB, QB, 1);
  for (int gi = 0; gi < G; gi += 3) {
    LOADG(PC, QC, gi + 2);
    STEPS(PA, QA, gi);
    if (gi + 1 < G) {
      LOADG(PA, QA, gi + 3);
      STEPS(PB, QB, gi + 1);
      if (gi + 2 < G) {
        LOADG(PB, QB, gi + 4);
        STEPS(PC, QC, gi + 2);
      }
    }
  }

  if (is_last) {
    __shared__ float fin[513];
    float* fp = fin + 8 * lane;
    fp[0] = a0; fp[1] = a1; fp[2] = a2; fp[3] = a3;
    fp[4] = a4; fp[5] = a5; fp[6] = a6; fp[7] = a7;
    if (lane == 63) fin[512] = a8;
    __syncthreads();
    if (lane == 0) {
      const int i1 = 2 * tl;
      const int i2 = (2 * tl - 1 > 0) ? (2 * tl - 1) : 0;
      float v = fin[i1] + ((tl > 0) ? fin[i2] : 0.f);
      v = fmaxf(v, 1e-37f);
      tot[b] = logf(v) + (float)E * 0.6931471805599453f;
    }
  } else {
    float* ap = alpha_g + (size_t)b * 520 + 8 * lane;
    ap[0] = a0; ap[1] = a1; ap[2] = a2; ap[3] = a3;
    ap[4] = a4; ap[5] = a5; ap[6] = a6; ap[7] = a7;
    if (lane == 63) alpha_g[(size_t)b * 520 + 512] = a8;
    if (lane == 0) exp_g[b] = E;
  }
}

// ---------------- K3: -mean over batch ----------------
__global__ void k3_mean(const float* __restrict__ tot, float* __restrict__ out,
                        int B) {
  float v = (threadIdx.x < B) ? tot[threadIdx.x] : 0.0f;
  v = wave_sum(v);
  if (threadIdx.x == 0) out[0] = -v / (float)B;
}

// ---------------- host ----------------
extern "C" void kernel_launch(void* const* d_in, const int* in_sizes, int n_in,
                              void* d_out, int out_size, void* d_ws,
                              size_t ws_size, hipStream_t stream) {
  const float* lp = (const float*)d_in[0];
  const int* targets = (const int*)d_in[1];
  const int* in_len = (const int*)d_in[2];
  const int* tgt_len = (const int*)d_in[3];
  float* out = (float*)d_out;

  const int B = in_sizes[2];               // 64
  const int S = in_sizes[1] / B;           // 256
  const int C = 1024;                      // fixed by reference
  const int T = (int)((size_t)in_sizes[0] / ((size_t)B * C));  // 2048

  // ws layout: tot[B pad 64] | exp_g[64 ints] | alpha_g[B*520] | g[B*Tc*GS]
  float* tot = (float*)d_ws;
  int* exp_g = (int*)(tot + 64);
  float* alpha_g = (float*)(exp_g + 64);
  float* g = alpha_g + (size_t)B * 520;
  const size_t head = (64 + 64 + (size_t)B * 520) * sizeof(float);

  int Tc = T;
  while (Tc > 32 && head + (size_t)B * Tc * GS * sizeof(float) > ws_size)
    Tc >>= 1;

  const int nch = (T + Tc - 1) / Tc;
  for (int c = 0; c < nch; ++c) {
    const int t0 = c * Tc;
    dim3 g1(Tc / 4, B);
    k1_gather<<<g1, 256, 0, stream>>>(lp, targets, g, t0, T, Tc, S, C);
    k2_alpha<<<B, 64, 0, stream>>>(g, targets, in_len, tgt_len, alpha_g, exp_g,
                                   tot, t0, Tc, S, (c == 0) ? 1 : 0,
                                   (c == nch - 1) ? 1 : 0);
  }
  k3_mean<<<1, 64, 0, stream>>>(tot, out, B);
}

// Round 3
// 338.374 us; speedup vs baseline: 3.2915x; 1.5441x over previous
//
#include <hip/hip_runtime.h>
#include <math.h>

#define GSB 264  // bf16 elements per gathered row (528 B): [p_tg0..255, blank@256, pad]

// ---------------- wave64 reductions ----------------
__device__ inline float wave_max(float v) {
#pragma unroll
  for (int off = 32; off > 0; off >>= 1) v = fmaxf(v, __shfl_xor(v, off, 64));
  return v;
}
__device__ inline float wave_sum(float v) {
#pragma unroll
  for (int off = 32; off > 0; off >>= 1) v += __shfl_xor(v, off, 64);
  return v;
}

// ---------------- K1: log-softmax + gather -> linear probs (bf16) --------
// grid: (Tc/4, B), block 256 (4 waves, one (b,t) row per wave)
__global__ __launch_bounds__(256) void k1_gather(
    const float* __restrict__ lp, const int* __restrict__ targets,
    unsigned short* __restrict__ g, int t0, int T, int Tc, int S, int C) {
  __shared__ __align__(16) float rowbuf[4][1024];
  const int w = threadIdx.x >> 6;
  const int lane = threadIdx.x & 63;
  const int tloc = blockIdx.x * 4 + w;
  const int b = blockIdx.y;
  const int t = t0 + tloc;

  const float* row = lp + ((size_t)b * T + t) * (size_t)C;

  float x[16];
#pragma unroll
  for (int j = 0; j < 4; ++j) {
    float4 v = *(const float4*)(row + j * 256 + lane * 4);
    x[4 * j + 0] = v.x; x[4 * j + 1] = v.y;
    x[4 * j + 2] = v.z; x[4 * j + 3] = v.w;
  }
  float m = x[0];
#pragma unroll
  for (int k = 1; k < 16; ++k) m = fmaxf(m, x[k]);
  m = wave_max(m);
  float s = 0.f;
#pragma unroll
  for (int k = 0; k < 16; ++k) s += __expf(x[k] - m);
  s = wave_sum(s);
  const float lse = m + __logf(s);

#pragma unroll
  for (int j = 0; j < 4; ++j) {
    *(float4*)(&rowbuf[w][j * 256 + lane * 4]) =
        make_float4(x[4 * j + 0], x[4 * j + 1], x[4 * j + 2], x[4 * j + 3]);
  }
  __syncthreads();

  unsigned short* gr = g + ((size_t)b * Tc + tloc) * GSB;
  const int* tg = targets + (size_t)b * S;
  for (int i = lane; i <= S; i += 64) {  // i==S is the blank slot (256)
    const int cls = (i == S) ? 0 : tg[i];
    const float p = __expf(rowbuf[w][cls] - lse);
    unsigned u = __float_as_uint(p);
    u = (u + 0x7fffu + ((u >> 16) & 1u)) >> 16;  // RNE to bf16
    gr[i] = (unsigned short)u;
  }
}

// ---------------- K2: linear-domain alpha recursion, 1 wave per batch ----
// lane l owns states [8l, 8l+8); lane 63 also owns state 512.
__global__ __launch_bounds__(64, 1) void k2_alpha(
    const unsigned short* __restrict__ g, const int* __restrict__ targets,
    const int* __restrict__ in_len, const int* __restrict__ tgt_len,
    float* __restrict__ alpha_g, int* __restrict__ exp_g,
    float* __restrict__ tot, int t0, int Tc, int S, int is_first, int is_last) {
  const int b = blockIdx.x;
  const int lane = threadIdx.x;
  const unsigned short* gb = g + (size_t)b * Tc * GSB;
  const int len = in_len[b];
  const int tl = tgt_len[b];
  const int* tg = targets + (size_t)b * S;

  // skip-transition multipliers for odd local states j=1,3,5,7
  const int4 mytg = *(const int4*)(tg + 4 * lane);
  const int tgm1 = (lane > 0) ? tg[4 * lane - 1] : -1;
  const float sk1 = (lane > 0 && mytg.x != tgm1) ? 1.f : 0.f;
  const float sk3 = (mytg.y != mytg.x) ? 1.f : 0.f;
  const float sk5 = (mytg.z != mytg.y) ? 1.f : 0.f;
  const float sk7 = (mytg.w != mytg.z) ? 1.f : 0.f;

  float a0, a1, a2, a3, a4, a5, a6, a7, a8;
  int E;
  int tstart;
  if (is_first) {
    a0 = a1 = a2 = a3 = a4 = a5 = a6 = a7 = a8 = 0.f;
    if (lane == 0) {
      a0 = __uint_as_float(((unsigned)gb[256]) << 16);  // blank
      a1 = __uint_as_float(((unsigned)gb[0]) << 16);    // first label
    }
    E = 0;
    tstart = 1;
  } else {
    const float* ap = alpha_g + (size_t)b * 520 + 8 * lane;
    a0 = ap[0]; a1 = ap[1]; a2 = ap[2]; a3 = ap[3];
    a4 = ap[4]; a5 = ap[5]; a6 = ap[6]; a7 = ap[7];
    a8 = (lane == 63) ? alpha_g[(size_t)b * 520 + 512] : 0.f;
    E = exp_g[b];
    tstart = t0;
  }

  const int t_hi = min(t0 + Tc, len);
  int N = t_hi - tstart; if (N < 0) N = 0;
  const int G = (N + 15) >> 4;  // 16-step tiles
  const int tsrel = tstart - t0;
  const int TcM1 = Tc - 1;

#define LOAD16(P, Q, gbase)                                  \
  {                                                          \
    _Pragma("unroll") for (int k = 0; k < 16; ++k) {         \
      int tr = tsrel + (gbase) * 16 + k;                     \
      tr = (tr < TcM1) ? tr : TcM1;                          \
      const unsigned short* rp = gb + (size_t)tr * GSB;      \
      P[k] = *(const ushort4*)(rp + 4 * lane);               \
      Q[k] = rp[256];                                        \
    }                                                        \
  }

#define STEP(pu, qu)                                            \
  {                                                             \
    const float pbv = __uint_as_float(((unsigned)(qu)) << 16);  \
    const float px = __uint_as_float(((unsigned)(pu).x) << 16); \
    const float py = __uint_as_float(((unsigned)(pu).y) << 16); \
    const float pz = __uint_as_float(((unsigned)(pu).z) << 16); \
    const float pw = __uint_as_float(((unsigned)(pu).w) << 16); \
    float hm1 = __shfl_up(a7, 1, 64);                           \
    hm1 = (lane == 0) ? 0.f : hm1;                              \
    const float n0 = (a0 + hm1) * pbv;                          \
    const float n1 = __fmaf_rn(sk1, hm1, a1 + a0) * px;         \
    const float n2 = (a2 + a1) * pbv;                           \
    const float n3 = __fmaf_rn(sk3, a1, a3 + a2) * py;          \
    const float n4 = (a4 + a3) * pbv;                           \
    const float n5 = __fmaf_rn(sk5, a3, a5 + a4) * pz;          \
    const float n6 = (a6 + a5) * pbv;                           \
    const float n7 = __fmaf_rn(sk7, a5, a7 + a6) * pw;          \
    const float n8 = (a8 + a7) * pbv;                           \
    a0 = n0; a1 = n1; a2 = n2; a3 = n3; a4 = n4;                \
    a5 = n5; a6 = n6; a7 = n7; a8 = n8;                         \
  }

#define RESCALE()                                                         \
  {                                                                       \
    float m_ = fmaxf(fmaxf(fmaxf(fmaxf(a0, a1), fmaxf(a2, a3)),           \
                           fmaxf(fmaxf(a4, a5), fmaxf(a6, a7))), a8);     \
    m_ = wave_max(m_);                                                    \
    const int e_ =                                                        \
        (m_ > 0.f) ? (int)((__float_as_uint(m_) >> 23) & 255u) - 127 : 0; \
    a0 = ldexpf(a0, -e_); a1 = ldexpf(a1, -e_); a2 = ldexpf(a2, -e_);     \
    a3 = ldexpf(a3, -e_); a4 = ldexpf(a4, -e_); a5 = ldexpf(a5, -e_);     \
    a6 = ldexpf(a6, -e_); a7 = ldexpf(a7, -e_); a8 = ldexpf(a8, -e_);     \
    E += e_;                                                              \
  }

#define DOTILE(P, Q, gbase)                                          \
  {                                                                  \
    const int rem = N - (gbase) * 16;                                \
    if (rem >= 16) {                                                 \
      STEP(P[0], Q[0]); STEP(P[1], Q[1]); STEP(P[2], Q[2]);          \
      STEP(P[3], Q[3]); STEP(P[4], Q[4]); STEP(P[5], Q[5]);          \
      STEP(P[6], Q[6]); STEP(P[7], Q[7]);                            \
      RESCALE();                                                     \
      STEP(P[8], Q[8]); STEP(P[9], Q[9]); STEP(P[10], Q[10]);        \
      STEP(P[11], Q[11]); STEP(P[12], Q[12]); STEP(P[13], Q[13]);    \
      STEP(P[14], Q[14]); STEP(P[15], Q[15]);                        \
      RESCALE();                                                     \
    } else if (rem > 0) {                                            \
      STEP(P[0], Q[0]);                                              \
      if (rem > 1) STEP(P[1], Q[1]);                                 \
      if (rem > 2) STEP(P[2], Q[2]);                                 \
      if (rem > 3) STEP(P[3], Q[3]);                                 \
      if (rem > 4) STEP(P[4], Q[4]);                                 \
      if (rem > 5) STEP(P[5], Q[5]);                                 \
      if (rem > 6) STEP(P[6], Q[6]);                                 \
      if (rem > 7) STEP(P[7], Q[7]);                                 \
      RESCALE();                                                     \
      if (rem > 8) {                                                 \
        STEP(P[8], Q[8]);                                            \
        if (rem > 9) STEP(P[9], Q[9]);                               \
        if (rem > 10) STEP(P[10], Q[10]);                            \
        if (rem > 11) STEP(P[11], Q[11]);                            \
        if (rem > 12) STEP(P[12], Q[12]);                            \
        if (rem > 13) STEP(P[13], Q[13]);                            \
        if (rem > 14) STEP(P[14], Q[14]);                            \
        RESCALE();                                                   \
      }                                                              \
    }                                                                \
  }

  ushort4 PA[16], PB[16], PC[16];
  unsigned short QA[16], QB[16], QC[16];
  LOAD16(PA, QA, 0);
  LOAD16(PB, QB, 1);
  for (int gi = 0; gi < G; gi += 3) {
    LOAD16(PC, QC, gi + 2);
    DOTILE(PA, QA, gi);
    if (gi + 1 < G) {
      LOAD16(PA, QA, gi + 3);
      DOTILE(PB, QB, gi + 1);
      if (gi + 2 < G) {
        LOAD16(PB, QB, gi + 4);
        DOTILE(PC, QC, gi + 2);
      }
    }
  }

  if (is_last) {
    __shared__ float fin[513];
    float* fp = fin + 8 * lane;
    fp[0] = a0; fp[1] = a1; fp[2] = a2; fp[3] = a3;
    fp[4] = a4; fp[5] = a5; fp[6] = a6; fp[7] = a7;
    if (lane == 63) fin[512] = a8;
    __syncthreads();
    if (lane == 0) {
      const int i1 = 2 * tl;
      const int i2 = (2 * tl - 1 > 0) ? (2 * tl - 1) : 0;
      float v = fin[i1] + ((tl > 0) ? fin[i2] : 0.f);
      v = fmaxf(v, 1e-37f);
      tot[b] = logf(v) + (float)E * 0.6931471805599453f;
    }
  } else {
    float* ap = alpha_g + (size_t)b * 520 + 8 * lane;
    ap[0] = a0; ap[1] = a1; ap[2] = a2; ap[3] = a3;
    ap[4] = a4; ap[5] = a5; ap[6] = a6; ap[7] = a7;
    if (lane == 63) alpha_g[(size_t)b * 520 + 512] = a8;
    if (lane == 0) exp_g[b] = E;
  }
}

// ---------------- K3: -mean over batch ----------------
__global__ void k3_mean(const float* __restrict__ tot, float* __restrict__ out,
                        int B) {
  float v = (threadIdx.x < B) ? tot[threadIdx.x] : 0.0f;
  v = wave_sum(v);
  if (threadIdx.x == 0) out[0] = -v / (float)B;
}

// ---------------- host ----------------
extern "C" void kernel_launch(void* const* d_in, const int* in_sizes, int n_in,
                              void* d_out, int out_size, void* d_ws,
                              size_t ws_size, hipStream_t stream) {
  const float* lp = (const float*)d_in[0];
  const int* targets = (const int*)d_in[1];
  const int* in_len = (const int*)d_in[2];
  const int* tgt_len = (const int*)d_in[3];
  float* out = (float*)d_out;

  const int B = in_sizes[2];               // 64
  const int S = in_sizes[1] / B;           // 256
  const int C = 1024;                      // fixed by reference
  const int T = (int)((size_t)in_sizes[0] / ((size_t)B * C));  // 2048

  // ws layout: tot[64] | exp_g[64 ints] | alpha_g[B*520 f32] | g[B*Tc*GSB bf16]
  float* tot = (float*)d_ws;
  int* exp_g = (int*)(tot + 64);
  float* alpha_g = (float*)(exp_g + 64);
  unsigned short* g = (unsigned short*)(alpha_g + (size_t)B * 520);
  const size_t head = (64 + 64 + (size_t)B * 520) * sizeof(float);

  int Tc = T;
  while (Tc > 32 && head + (size_t)B * Tc * GSB * 2 > ws_size) Tc >>= 1;

  const int nch = (T + Tc - 1) / Tc;
  for (int c = 0; c < nch; ++c) {
    const int t0 = c * Tc;
    dim3 g1(Tc / 4, B);
    k1_gather<<<g1, 256, 0, stream>>>(lp, targets, g, t0, T, Tc, S, C);
    k2_alpha<<<B, 64, 0, stream>>>(g, targets, in_len, tgt_len, alpha_g, exp_g,
                                   tot, t0, Tc, S, (c == 0) ? 1 : 0,
                                   (c == nch - 1) ? 1 : 0);
  }
  k3_mean<<<1, 64, 0, stream>>>(tot, out, B);
}